// Round 10
// baseline (477.814 us; speedup 1.0000x reference)
//
#include <hip/hip_runtime.h>

#define N_NODES 86016
#define N_EDGES 4194304
#define HID 32
#define B_GR 1024
#define NPG 84
#define NEG 0.2f

#define NCH 512       // chunks
#define CHE 8192      // edges per chunk; NCH*CHE == N_EDGES
#define NB  512       // dst buckets
#define NPB 168       // nodes per bucket; NB*NPB == N_NODES
#define SRCMASK 0x1FFFF   // 17 bits (N_NODES < 2^17)

typedef float floatx2 __attribute__((ext_vector_type(2)));
typedef float f32x4 __attribute__((ext_vector_type(4)));
typedef short bf16x8 __attribute__((ext_vector_type(8)));

// ---- workspace layout (bytes) ---- (R6 layout + asE)
constexpr size_t O_REC   = 0;                                    // E * 8
constexpr size_t O_CM    = O_REC  + (size_t)N_EDGES * 8;         // NB*NCH int
constexpr size_t O_HT    = O_CM   + (size_t)NB * NCH * 4;        // N*32 fp8
constexpr size_t O_HB    = O_HT   + (size_t)N_NODES * HID;       // N*32 f32
constexpr size_t O_AS    = O_HB   + (size_t)N_NODES * HID * 4;   // N f32
constexpr size_t O_AD    = O_AS   + (size_t)N_NODES * 4;         // N f32
constexpr size_t O_ROW   = O_AD   + (size_t)N_NODES * 4;         // N+1 int
constexpr size_t O_BTOT  = O_ROW  + (size_t)(N_NODES + 1) * 4 + 12; // NB int
constexpr size_t O_BBASE = O_BTOT + (size_t)NB * 4;              // NB+1 int
constexpr size_t O_FOLD  = O_BBASE + (size_t)(NB + 1) * 4 + 12;  // 8 f32
constexpr size_t O_ASE   = O_FOLD + 64;                          // E f32 (16.8 MB)

__device__ __forceinline__ unsigned short f2bf(float f) {
    unsigned u = __float_as_uint(f);
    u += 0x7FFFu + ((u >> 16) & 1u);      // round-to-nearest-even
    return (unsigned short)(u >> 16);
}

// ---- CSR build (R6 five-kernel version: contiguous rec, known-good) ----
__global__ __launch_bounds__(1024) void k_hist(const int* __restrict__ dst, int* __restrict__ cm) {
    __shared__ int cnt[NB];
    int t = threadIdx.x, c = blockIdx.x;
    if (t < NB) cnt[t] = 0;
    __syncthreads();
    int base = c * CHE;
#pragma unroll
    for (int k = 0; k < 8; ++k) {
        int d = dst[base + k * 1024 + t];
        atomicAdd(&cnt[(unsigned)d / NPB], 1);
    }
    __syncthreads();
    if (t < NB) cm[t * NCH + c] = cnt[t];
}

__global__ __launch_bounds__(512) void k_scanchunks(int* __restrict__ cm, int* __restrict__ btot) {
    __shared__ int sa[NCH], sb[NCH];
    int b = blockIdx.x, t = threadIdx.x;
    sa[t] = cm[b * NCH + t];
    __syncthreads();
    int* s = sa; int* d = sb;
    for (int off = 1; off < NCH; off <<= 1) {
        d[t] = s[t] + (t >= off ? s[t - off] : 0);
        __syncthreads();
        int* tmp = s; s = d; d = tmp;
    }
    cm[b * NCH + t] = t ? s[t - 1] : 0;
    if (t == 0) btot[b] = s[NCH - 1];
}

__global__ void k_scanbuckets(const int* __restrict__ btot, int* __restrict__ bbase,
                              int* __restrict__ row,
                              const float* __restrict__ We, const float* __restrict__ ae,
                              float* __restrict__ fold) {
    __shared__ int sa[NB], sb[NB];
    int t = threadIdx.x;
    if (t < 8) {
        int l = t >> 1, c = t & 1;
        float s = 0.f;
        for (int j = 0; j < 32; ++j) s += We[l * 64 + c * 32 + j] * ae[l * 32 + j];
        fold[t] = s;
    }
    sa[t] = btot[t];
    __syncthreads();
    int* s = sa; int* d = sb;
    for (int off = 1; off < NB; off <<= 1) {
        d[t] = s[t] + (t >= off ? s[t - off] : 0);
        __syncthreads();
        int* tmp = s; s = d; d = tmp;
    }
    bbase[t] = t ? s[t - 1] : 0;
    if (t == NB - 1) { bbase[NB] = s[NB - 1]; row[N_NODES] = s[NB - 1]; }
}

__global__ __launch_bounds__(1024) void k_place(const int* __restrict__ ei,
                                                const float2* __restrict__ ea,
                                                const int* __restrict__ cm,
                                                const int* __restrict__ bbase,
                                                int2* __restrict__ rec) {
    __shared__ int cnt[NB];
    __shared__ int base[NB];
    int t = threadIdx.x, c = blockIdx.x;
    if (t < NB) cnt[t] = 0;
    __syncthreads();
    int eb = c * CHE;
    int wd0[8], bin[8], rnk[8];
    unsigned pk[8];
#pragma unroll
    for (int k = 0; k < 8; ++k) {
        int e = eb + k * 1024 + t;
        int s = ei[e];
        int d = ei[N_EDGES + e];
        float2 a = ea[e];
        int b = (unsigned)d / NPB;
        int dn = d - b * NPB;
        wd0[k] = s | (dn << 17);
        pk[k] = ((unsigned)f2bf(a.y) << 16) | f2bf(a.x);
        bin[k] = b;
        rnk[k] = atomicAdd(&cnt[b], 1);
    }
    __syncthreads();
    if (t < NB) base[t] = bbase[t] + cm[t * NCH + c];
    __syncthreads();
#pragma unroll
    for (int k = 0; k < 8; ++k)
        rec[base[bin[k]] + rnk[k]] = make_int2(wd0[k], (int)pk[k]);
}

__global__ __launch_bounds__(1024) void k_sort(int2* __restrict__ rec,
                                               const int* __restrict__ bbase,
                                               int* __restrict__ row) {
    __shared__ int cnt[256], tmp[256], ebase[256];
    int b = blockIdx.x, t = threadIdx.x;
    int n0 = b * NPB;
    int beg = bbase[b], end = bbase[b + 1], m = end - beg;
    if (t < 256) cnt[t] = 0;
    __syncthreads();
    int2 rv[12];
    int dr[12];
    int cv = 0;
    for (int i = t; i < m; i += 1024) {
        int2 r = rec[beg + i];
        int dn = ((unsigned)r.x >> 17) & 0xFF;
        int rnk = atomicAdd(&cnt[dn], 1);
        if (cv < 12) { rv[cv] = r; dr[cv] = dn | (rnk << 8); }
        cv++;                 // m <= 12288 always (bucket ~8192 + 45 sigma)
    }
    __syncthreads();
    int* s = cnt; int* d = tmp;
    for (int off = 1; off < 256; off <<= 1) {
        int v = 0;
        if (t < 256) v = s[t] + (t >= off ? s[t - off] : 0);
        __syncthreads();
        if (t < 256) d[t] = v;
        __syncthreads();
        int* tp = s; s = d; d = tp;
    }
    if (t < 256) ebase[t] = t ? s[t - 1] : 0;
    __syncthreads();
    if (t < NPB) row[n0 + t] = beg + ebase[t];
    int ncv = cv < 12 ? cv : 12;
    for (int k = 0; k < ncv; ++k) {
        int dn = dr[k] & 0xFF;
        int rnk = dr[k] >> 8;
        rec[beg + ebase[dn] + rnk] = rv[k];
    }
}

// ---- per-layer as_arr -> per-edge asE expansion ----
// Pure edge-space gather: 8 independent as_arr gathers per thread (as_arr is
// 344 KB = L2-resident), rec.x read streaming, asE written coalesced. This
// hoists k_gather's per-edge random as-line (1 of its 2.06 lines/edge) into a
// kernel with full memory-level parallelism.
__global__ __launch_bounds__(1024) void k_ase(const int* __restrict__ recx,
                                              const float* __restrict__ as_arr,
                                              float* __restrict__ asE) {
    int e0 = blockIdx.x * CHE + threadIdx.x;
    int s[8];
#pragma unroll
    for (int k = 0; k < 8; ++k) s[k] = recx[(e0 + k * 1024) * 2] & SRCMASK;
    float v[8];
#pragma unroll
    for (int k = 0; k < 8; ++k) v[k] = as_arr[s[k]];
#pragma unroll
    for (int k = 0; k < 8; ++k) asE[e0 + k * 1024] = v[k];
}

// pack two f32 (this lane = even j, partner = j+1) into fp8x2 via the NATIVE
// v_cvt_pk_fp8_f32 and store 16 bits. (32 B rows: n<<4 shorts)
__device__ __forceinline__ void store_fp8_pair(unsigned short* __restrict__ hout,
                                               int n, int j, float acc) {
    float p = __shfl_xor(acc, 1);   // even j: p = acc of j+1
    if (!(j & 1)) {
        int pk = __builtin_amdgcn_cvt_pk_fp8_f32(acc, p, 0, false);
        hout[(n << 4) + (j >> 1)] = (unsigned short)pk;
    }
}

__global__ void k_transform0(const float* __restrict__ x, const float* __restrict__ W0,
                             const float* __restrict__ as_w, const float* __restrict__ ad_w,
                             unsigned short* __restrict__ hout, float* __restrict__ as_arr,
                             float* __restrict__ ad_arr) {
    int tid = blockIdx.x * 256 + threadIdx.x;
    int j = tid & 31;
    int n = tid >> 5;
    float acc = x[n] * W0[j];
    store_fp8_pair(hout, n, j, acc);
    float v1 = acc * as_w[j], v2 = acc * ad_w[j];
#pragma unroll
    for (int m = 16; m >= 1; m >>= 1) {
        v1 += __shfl_xor(v1, m);
        v2 += __shfl_xor(v2, m);
    }
    if (j == 0) { as_arr[n] = v1; ad_arr[n] = v2; }
}

// MFMA transform: h_out = h_in @ W via mfma_f32_16x16x32_bf16 (R6, ~4 us).
__global__ void k_transform_m(const float* __restrict__ hin, const float* __restrict__ W,
                              const float* __restrict__ as_w, const float* __restrict__ ad_w,
                              unsigned short* __restrict__ hout, float* __restrict__ as_arr,
                              float* __restrict__ ad_arr) {
    int lane = threadIdx.x & 63;
    int wv = threadIdx.x >> 6;
    int col = lane & 15, hi = lane >> 4;
    int nb = (blockIdx.x * 4 + wv) * 64;     // 4 tiles x 16 nodes per wave
    bf16x8 b0, b1;
#pragma unroll
    for (int e = 0; e < 8; ++e) {
        b0[e] = (short)f2bf(W[(hi * 8 + e) * 32 + col]);
        b1[e] = (short)f2bf(W[(hi * 8 + e) * 32 + col + 16]);
    }
    float asw0 = as_w[col], asw1 = as_w[col + 16];
    float adw0 = ad_w[col], adw1 = ad_w[col + 16];
    float4 a0[4], a1[4];
#pragma unroll
    for (int t = 0; t < 4; ++t) {
        const float* r = hin + (size_t)(nb + t * 16 + col) * 32 + hi * 8;
        a0[t] = *(const float4*)r;
        a1[t] = *(const float4*)(r + 4);
    }
    int* hw = (int*)hout;
#pragma unroll
    for (int t = 0; t < 4; ++t) {
        bf16x8 a;
        a[0] = (short)f2bf(a0[t].x); a[1] = (short)f2bf(a0[t].y);
        a[2] = (short)f2bf(a0[t].z); a[3] = (short)f2bf(a0[t].w);
        a[4] = (short)f2bf(a1[t].x); a[5] = (short)f2bf(a1[t].y);
        a[6] = (short)f2bf(a1[t].z); a[7] = (short)f2bf(a1[t].w);
        f32x4 z = {0.f, 0.f, 0.f, 0.f};
        f32x4 c0 = __builtin_amdgcn_mfma_f32_16x16x32_bf16(a, b0, z, 0, 0, 0);
        f32x4 c1 = __builtin_amdgcn_mfma_f32_16x16x32_bf16(a, b1, z, 0, 0, 0);
        int n0t = nb + t * 16;
#pragma unroll
        for (int i = 0; i < 4; ++i) {
            float pa = c0[i] * asw0 + c1[i] * asw1;
            float pd = c0[i] * adw0 + c1[i] * adw1;
#pragma unroll
            for (int m = 1; m <= 8; m <<= 1) {
                pa += __shfl_xor(pa, m);
                pd += __shfl_xor(pd, m);
            }
            float e0 = __shfl_xor(c0[i], 1), e1 = __shfl_xor(c1[i], 1);
            int pk0 = __builtin_amdgcn_cvt_pk_fp8_f32(c0[i], e0, 0, false);
            int pk1 = __builtin_amdgcn_cvt_pk_fp8_f32(c1[i], e1, 0, false);
            int q0 = __shfl_xor(pk0, 2), q1 = __shfl_xor(pk1, 2);
            int n = n0t + hi * 4 + i;
            if ((col & 3) == 0) {
                int w0 = (pk0 & 0xFFFF) | (q0 << 16);
                int w1 = (pk1 & 0xFFFF) | (q1 << 16);
                hw[(n << 3) + (col >> 2)] = w0;
                hw[(n << 3) + 4 + (col >> 2)] = w1;
            }
            if (col == 0) { as_arr[n] = pa; ad_arr[n] = pd; }
        }
    }
}

// accumulate one 4-fp8 word (4 dims) into 2 packed f32x2 accumulators
__device__ __forceinline__ void acc_word(float wp, int word, floatx2* acc) {
    floatx2 v01 = __builtin_amdgcn_cvt_pk_f32_fp8(word, false);
    floatx2 v23 = __builtin_amdgcn_cvt_pk_f32_fp8(word, true);
    floatx2 w2 = {wp, wp};
    acc[0] = __builtin_elementwise_fma(w2, v01, acc[0]);
    acc[1] = __builtin_elementwise_fma(w2, v23, acc[1]);
}

// k_gather: R6 structure, but alpha_src comes from the STREAMING asE array
// (coalesced, loaded alongside rec) instead of a per-edge random gather.
// Random lines/edge: 2.06 -> 1.06.
__global__ void k_gather(const unsigned short* __restrict__ hT, const int2* __restrict__ rec,
                         const int* __restrict__ row, const float* __restrict__ asE,
                         const float* __restrict__ as_arr, const float* __restrict__ ad_arr,
                         const float* __restrict__ fold, const float* __restrict__ bias,
                         float* __restrict__ out, int do_relu) {
    const int* hw = (const int*)hT;     // row n = hw[n*8 + dl], 4 fp8 each
    __shared__ int2   exS[4][64];
    __shared__ float2 exW[4][64];
    int lane = threadIdx.x & 63;
    int wv = threadIdx.x >> 6;
    int slot = lane >> 3;     // 0..7
    int dl = lane & 7;        // 0..7 (dims dl*4 .. dl*4+3)
    const int* hwd = hw + dl;           // per-lane base; index with s<<3
    int nb = blockIdx.x * 16 + wv * 4;  // this wave's 4 nodes (2 pairs)
    int rowv[5];
#pragma unroll
    for (int i = 0; i < 5; ++i) rowv[i] = row[nb + i];
    float f0 = fold[0], f1 = fold[1];
    float4 bi = *(const float4*)(bias + 4 * dl);
    floatx2 zz = {0.f, 0.f};

    // ---- issue all rec + asE loads up-front (both streaming/coalesced) ----
    int2 r0[2], r1[2];
    float ae0[2], ae1[2];
#pragma unroll
    for (int k = 0; k < 2; ++k) {
        int beg0 = rowv[2 * k], end0 = rowv[2 * k + 1];
        int beg1 = rowv[2 * k + 1], end1 = rowv[2 * k + 2];
        int i0 = beg0 + lane; i0 = (i0 < end0) ? i0 : 0;
        int i1 = beg1 + lane; i1 = (i1 < end1) ? i1 : 0;
        r0[k] = rec[i0];
        r1[k] = rec[i1];
        ae0[k] = asE[i0];
        ae1[k] = asE[i1];
    }

#pragma unroll
    for (int k = 0; k < 2; ++k) {
        int beg0 = rowv[2 * k], end0 = rowv[2 * k + 1];
        int beg1 = rowv[2 * k + 1], end1 = rowv[2 * k + 2];
        int n0 = nb + 2 * k, n1 = n0 + 1;
        bool act0 = (beg0 + lane) < end0;
        bool act1 = (beg1 + lane) < end1;
        int s0 = r0[k].x & SRCMASK;
        int s1 = r1[k].x & SRCMASK;
        exS[wv][lane] = make_int2(s0 << 3, s1 << 3);
        int h0[8], h1[8];
#pragma unroll
        for (int p = 0; p < 8; ++p) {
            int2 sp = exS[wv][p * 8 + slot];
            h0[p] = hwd[sp.x];
            h1[p] = hwd[sp.y];
        }
        float a0 = ae0[k], a1 = ae1[k];
        float cd0 = ad_arr[n0], cd1 = ad_arr[n1];
        float ax0 = __uint_as_float((unsigned)r0[k].y << 16);
        float ay0 = __uint_as_float((unsigned)r0[k].y & 0xFFFF0000u);
        float ax1 = __uint_as_float((unsigned)r1[k].y << 16);
        float ay1 = __uint_as_float((unsigned)r1[k].y & 0xFFFF0000u);
        float ed0 = fmaf(ax0, f0, ay0 * f1);
        float ed1 = fmaf(ax1, f0, ay1 * f1);
        float lg0 = a0 + cd0 + ed0; lg0 = fmaxf(lg0, NEG * lg0);
        float lg1 = a1 + cd1 + ed1; lg1 = fmaxf(lg1, NEG * lg1);
        float w0 = act0 ? __expf(lg0) : 0.f;
        float w1 = act1 ? __expf(lg1) : 0.f;
        exW[wv][lane] = make_float2(w0, w1);
        float den0 = w0, den1 = w1;
        float es0 = act0 ? ed0 : 0.f;
        float es1 = act1 ? ed1 : 0.f;
        floatx2 acc0[2] = {zz, zz};
        floatx2 acc1[2] = {zz, zz};
#pragma unroll
        for (int p = 0; p < 8; ++p) {
            float2 wp = exW[wv][p * 8 + slot];
            acc_word(wp.x, h0[p], acc0);
            acc_word(wp.y, h1[p], acc1);
        }
        if (end0 - beg0 > 64 || end1 - beg1 > 64) {
            for (int e0 = beg0 + 64, e1 = beg1 + 64; e0 < end0 || e1 < end1;
                 e0 += 64, e1 += 64) {
                int i0 = e0 + lane; bool c0 = i0 < end0; i0 = c0 ? i0 : 0;
                int i1 = e1 + lane; bool c1 = i1 < end1; i1 = c1 ? i1 : 0;
                int2 q0 = rec[i0], q1 = rec[i1];
                float b0 = asE[i0], b1 = asE[i1];
                int t0 = q0.x & SRCMASK, t1 = q1.x & SRCMASK;
                exS[wv][lane] = make_int2(t0 << 3, t1 << 3);
                int g0[8], g1[8];
#pragma unroll
                for (int p = 0; p < 8; ++p) {
                    int2 sp = exS[wv][p * 8 + slot];
                    g0[p] = hwd[sp.x];
                    g1[p] = hwd[sp.y];
                }
                float bx0 = __uint_as_float((unsigned)q0.y << 16);
                float by0 = __uint_as_float((unsigned)q0.y & 0xFFFF0000u);
                float bx1 = __uint_as_float((unsigned)q1.y << 16);
                float by1 = __uint_as_float((unsigned)q1.y & 0xFFFF0000u);
                float fd0 = fmaf(bx0, f0, by0 * f1);
                float fd1 = fmaf(bx1, f0, by1 * f1);
                float mg0 = b0 + cd0 + fd0; mg0 = fmaxf(mg0, NEG * mg0);
                float mg1 = b1 + cd1 + fd1; mg1 = fmaxf(mg1, NEG * mg1);
                float v0 = c0 ? __expf(mg0) : 0.f;
                float v1 = c1 ? __expf(mg1) : 0.f;
                exW[wv][lane] = make_float2(v0, v1);
                den0 += v0; den1 += v1;
                es0 += c0 ? fd0 : 0.f;
                es1 += c1 ? fd1 : 0.f;
#pragma unroll
                for (int p = 0; p < 8; ++p) {
                    float2 wp = exW[wv][p * 8 + slot];
                    acc_word(wp.x, g0[p], acc0);
                    acc_word(wp.y, g1[p], acc1);
                }
            }
        }
        // ---- epilogue ----
        float* fA = (float*)acc0;
        float* fB = (float*)acc1;
#pragma unroll
        for (int m = 8; m <= 32; m <<= 1) {
#pragma unroll
            for (int q = 0; q < 4; ++q) {
                fA[q] += __shfl_xor(fA[q], m);
                fB[q] += __shfl_xor(fB[q], m);
            }
        }
#pragma unroll
        for (int m = 1; m <= 32; m <<= 1) {
            den0 += __shfl_xor(den0, m);
            den1 += __shfl_xor(den1, m);
            es0 += __shfl_xor(es0, m);
            es1 += __shfl_xor(es1, m);
        }
        int dg0 = end0 - beg0, dg1 = end1 - beg1;
        float el0 = es0 / fmaxf((float)dg0, 1.0f);
        float el1 = es1 / fmaxf((float)dg1, 1.0f);
        float lgs0 = as_arr[n0] + cd0 + el0; lgs0 = fmaxf(lgs0, NEG * lgs0);
        float lgs1 = as_arr[n1] + cd1 + el1; lgs1 = fmaxf(lgs1, NEG * lgs1);
        float ws0 = __expf(lgs0), ws1 = __expf(lgs1);
        den0 += ws0; den1 += ws1;
        acc_word(ws0, hwd[n0 << 3], acc0);   // self rows (uniform per wave)
        acc_word(ws1, hwd[n1 << 3], acc1);
        float rd0 = 1.0f / den0, rd1 = 1.0f / den1;
        float4 o0 = {fA[0] * rd0 + bi.x, fA[1] * rd0 + bi.y,
                     fA[2] * rd0 + bi.z, fA[3] * rd0 + bi.w};
        float4 o1 = {fB[0] * rd1 + bi.x, fB[1] * rd1 + bi.y,
                     fB[2] * rd1 + bi.z, fB[3] * rd1 + bi.w};
        if (do_relu) {
            o0.x = fmaxf(o0.x, 0.f); o0.y = fmaxf(o0.y, 0.f);
            o0.z = fmaxf(o0.z, 0.f); o0.w = fmaxf(o0.w, 0.f);
            o1.x = fmaxf(o1.x, 0.f); o1.y = fmaxf(o1.y, 0.f);
            o1.z = fmaxf(o1.z, 0.f); o1.w = fmaxf(o1.w, 0.f);
        }
        if (slot == 0) {
            *(float4*)(out + (n0 << 5) + (dl << 2)) = o0;
            *(float4*)(out + (n1 << 5) + (dl << 2)) = o1;
        }
    }
}

__global__ void k_pool(const float* __restrict__ h, const float* __restrict__ lw,
                       const float* __restrict__ lb, float* __restrict__ out) {
    int lane = threadIdx.x & 63;
    int g = blockIdx.x * 4 + (threadIdx.x >> 6);
    int j = lane & 31;
    int half = lane >> 5;
    const float* base = h + (size_t)g * NPG * HID;
    float acc = 0.f;
    for (int i = half; i < NPG; i += 2) acc += base[i * HID + j];
    acc += __shfl_xor(acc, 32);
    float v = acc * lw[j];
#pragma unroll
    for (int m = 16; m >= 1; m >>= 1) v += __shfl_xor(v, m);
    if (lane == 0) out[g] = fmaxf(v + lb[0], 0.f);
}

extern "C" void kernel_launch(void* const* d_in, const int* in_sizes, int n_in,
                              void* d_out, int out_size, void* d_ws, size_t ws_size,
                              hipStream_t stream) {
    const float* x        = (const float*)d_in[0];
    const int*   ei       = (const int*)d_in[1];
    const float* eattr    = (const float*)d_in[2];
    const float* W0       = (const float*)d_in[3];
    const float* Ws       = (const float*)d_in[4];
    const float* att_src  = (const float*)d_in[5];
    const float* att_dst  = (const float*)d_in[6];
    const float* We       = (const float*)d_in[7];
    const float* att_edge = (const float*)d_in[8];
    const float* bias     = (const float*)d_in[9];
    const float* lin_w    = (const float*)d_in[10];
    const float* lin_b    = (const float*)d_in[11];
    float* out = (float*)d_out;

    char* w = (char*)d_ws;
    int2*           rec    = (int2*)(w + O_REC);
    int*            cm     = (int*)(w + O_CM);
    unsigned short* hT     = (unsigned short*)(w + O_HT);
    float*          hB     = (float*)(w + O_HB);
    float*          as_arr = (float*)(w + O_AS);
    float*          ad_arr = (float*)(w + O_AD);
    int*            row    = (int*)(w + O_ROW);
    int*            btot   = (int*)(w + O_BTOT);
    int*            bbase  = (int*)(w + O_BBASE);
    float*          fold   = (float*)(w + O_FOLD);
    float*          asE    = (float*)(w + O_ASE);

    // ---- CSR build (R6 five-kernel, write-clustered, contiguous rec) ----
    k_hist<<<NCH, 1024, 0, stream>>>(ei + N_EDGES, cm);
    k_scanchunks<<<NB, 512, 0, stream>>>(cm, btot);
    k_scanbuckets<<<1, NB, 0, stream>>>(btot, bbase, row, We, att_edge, fold);
    k_place<<<NCH, 1024, 0, stream>>>(ei, (const float2*)eattr, cm, bbase, rec);
    k_sort<<<NB, 1024, 0, stream>>>(rec, bbase, row);

    // ---- layer 0 ----
    k_transform0<<<N_NODES * HID / 256, 256, 0, stream>>>(x, W0, att_src, att_dst,
                                                          hT, as_arr, ad_arr);
    k_ase<<<NCH, 1024, 0, stream>>>((const int*)rec, as_arr, asE);
    k_gather<<<N_NODES / 16, 256, 0, stream>>>(hT, rec, row, asE, as_arr, ad_arr,
                                               fold, bias, hB, 1);
    // ---- layers 1..3 ----
    for (int l = 1; l < 4; ++l) {
        k_transform_m<<<N_NODES / 256, 256, 0, stream>>>(
            hB, Ws + (size_t)(l - 1) * HID * HID, att_src + l * HID, att_dst + l * HID,
            hT, as_arr, ad_arr);
        k_ase<<<NCH, 1024, 0, stream>>>((const int*)rec, as_arr, asE);
        k_gather<<<N_NODES / 16, 256, 0, stream>>>(hT, rec, row, asE, as_arr, ad_arr,
                                                   fold + 2 * l, bias + l * HID, hB,
                                                   (l < 3) ? 1 : 0);
    }

    // ---- pool + linear + relu ----
    k_pool<<<B_GR / 4, 256, 0, stream>>>(hB, lin_w, lin_b, out);
}

// Round 11
// 421.630 us; speedup vs baseline: 1.1333x; 1.1333x over previous
//
#include <hip/hip_runtime.h>

#define N_NODES 86016
#define N_EDGES 4194304
#define HID 32
#define B_GR 1024
#define NPG 84
#define NEG 0.2f

#define NCH 1024      // chunks
#define CHE 4096      // edges per chunk; NCH*CHE == N_EDGES
#define NB  512       // dst buckets
#define NPB 168       // nodes per bucket; NB*NPB == N_NODES
#define SRCMASK 0x1FFFF   // 17 bits (N_NODES < 2^17)

typedef float floatx2 __attribute__((ext_vector_type(2)));
typedef float f32x4 __attribute__((ext_vector_type(4)));
typedef short bf16x8 __attribute__((ext_vector_type(8)));

// ---- workspace layout (bytes) ----
constexpr size_t O_REC   = 0;                                    // E * 8
constexpr size_t O_CM    = O_REC  + (size_t)N_EDGES * 8;         // NB*NCH int (2MB)
constexpr size_t O_HT    = O_CM   + (size_t)NB * NCH * 4;        // N*32 fp8
constexpr size_t O_HB    = O_HT   + (size_t)N_NODES * HID;       // N*32 f32
constexpr size_t O_AS    = O_HB   + (size_t)N_NODES * HID * 4;   // N f32
constexpr size_t O_AD    = O_AS   + (size_t)N_NODES * 4;         // N f32
constexpr size_t O_ROW   = O_AD   + (size_t)N_NODES * 4;         // N+1 int
constexpr size_t O_BTOT  = O_ROW  + (size_t)(N_NODES + 1) * 4 + 12; // NB int
constexpr size_t O_BBASE = O_BTOT + (size_t)NB * 4;              // NB+1 int
constexpr size_t O_FOLD  = O_BBASE + (size_t)(NB + 1) * 4 + 12;  // 8 f32
constexpr size_t O_ASE   = O_FOLD + 64;                          // E f32 (16.8 MB)

__device__ __forceinline__ unsigned short f2bf(float f) {
    unsigned u = __float_as_uint(f);
    u += 0x7FFFu + ((u >> 16) & 1u);      // round-to-nearest-even
    return (unsigned short)(u >> 16);
}

// ---- CSR build ----
__global__ __launch_bounds__(512) void k_hist(const int* __restrict__ dst, int* __restrict__ cm) {
    __shared__ int cnt[NB];
    int t = threadIdx.x, c = blockIdx.x;
    cnt[t] = 0;
    __syncthreads();
    int base = c * CHE;
#pragma unroll
    for (int k = 0; k < 8; ++k) {
        int d = dst[base + k * 512 + t];
        atomicAdd(&cnt[(unsigned)d / NPB], 1);
    }
    __syncthreads();
    cm[t * NCH + c] = cnt[t];
}

__global__ __launch_bounds__(1024) void k_scanchunks(int* __restrict__ cm, int* __restrict__ btot) {
    __shared__ int sa[NCH], sb[NCH];
    int b = blockIdx.x, t = threadIdx.x;
    sa[t] = cm[b * NCH + t];
    __syncthreads();
    int* s = sa; int* d = sb;
    for (int off = 1; off < NCH; off <<= 1) {
        d[t] = s[t] + (t >= off ? s[t - off] : 0);
        __syncthreads();
        int* tmp = s; s = d; d = tmp;
    }
    cm[b * NCH + t] = t ? s[t - 1] : 0;
    if (t == 0) btot[b] = s[NCH - 1];
}

__global__ void k_scanbuckets(const int* __restrict__ btot, int* __restrict__ bbase,
                              int* __restrict__ row,
                              const float* __restrict__ We, const float* __restrict__ ae,
                              float* __restrict__ fold) {
    __shared__ int sa[NB], sb[NB];
    int t = threadIdx.x;
    if (t < 8) {
        int l = t >> 1, c = t & 1;
        float s = 0.f;
        for (int j = 0; j < 32; ++j) s += We[l * 64 + c * 32 + j] * ae[l * 32 + j];
        fold[t] = s;
    }
    sa[t] = btot[t];
    __syncthreads();
    int* s = sa; int* d = sb;
    for (int off = 1; off < NB; off <<= 1) {
        d[t] = s[t] + (t >= off ? s[t - off] : 0);
        __syncthreads();
        int* tmp = s; s = d; d = tmp;
    }
    bbase[t] = t ? s[t - 1] : 0;
    if (t == NB - 1) { bbase[NB] = s[NB - 1]; row[N_NODES] = s[NB - 1]; }
}

// LDS-staged placement: records staged in LDS ordered by bucket, then copied
// out with consecutive lanes -> consecutive final addresses (full-line wave
// stores). Same rec layout as the scatter version, bitwise. Kills the 3.4x
// partial-line writeback amplification (R10: WRITE 115 MB for 33.5 MB payload).
__global__ __launch_bounds__(512) void k_place(const int* __restrict__ ei,
                                               const float2* __restrict__ ea,
                                               const int* __restrict__ cm,
                                               const int* __restrict__ bbase,
                                               int2* __restrict__ rec) {
    __shared__ int cnt[NB];
    __shared__ int s1[NB], s2[NB];
    __shared__ int loc[NB + 1];
    __shared__ int base[NB];
    __shared__ int2 st[CHE];          // 32 KB staging
    int t = threadIdx.x, c = blockIdx.x;
    cnt[t] = 0;
    __syncthreads();
    int eb = c * CHE;
    int wd0[8], bin[8], rnk[8];
    unsigned pk[8];
#pragma unroll
    for (int k = 0; k < 8; ++k) {
        int e = eb + k * 512 + t;
        int s = ei[e];
        int d = ei[N_EDGES + e];
        float2 a = ea[e];
        int b = (unsigned)d / NPB;
        int dn = d - b * NPB;
        wd0[k] = s | (dn << 17);
        pk[k] = ((unsigned)f2bf(a.y) << 16) | f2bf(a.x);
        bin[k] = b;
        rnk[k] = atomicAdd(&cnt[b], 1);
    }
    __syncthreads();
    // exclusive scan of cnt -> loc (staging run offsets)
    s1[t] = cnt[t];
    __syncthreads();
    int* s = s1; int* d2 = s2;
    for (int off = 1; off < NB; off <<= 1) {
        d2[t] = s[t] + (t >= off ? s[t - off] : 0);
        __syncthreads();
        int* tmp = s; s = d2; d2 = tmp;
    }
    loc[t] = t ? s[t - 1] : 0;
    if (t == 0) loc[NB] = CHE;
    base[t] = bbase[t] + cm[t * NCH + c];
    __syncthreads();
#pragma unroll
    for (int k = 0; k < 8; ++k)
        st[loc[bin[k]] + rnk[k]] = make_int2(wd0[k], (int)pk[k]);
    __syncthreads();
    // coalesced copy-out: staging position i -> rec[base[b] + (i - loc[b])]
    for (int i = t; i < CHE; i += 512) {
        int lo = 0, hi = NB;
        while (hi - lo > 1) {
            int mid = (lo + hi) >> 1;
            if (loc[mid] <= i) lo = mid; else hi = mid;
        }
        rec[base[lo] + (i - loc[lo])] = st[i];
    }
}

__global__ __launch_bounds__(1024) void k_sort(int2* __restrict__ rec,
                                               const int* __restrict__ bbase,
                                               int* __restrict__ row) {
    __shared__ int cnt[256], tmp[256], ebase[256];
    int b = blockIdx.x, t = threadIdx.x;
    int n0 = b * NPB;
    int beg = bbase[b], end = bbase[b + 1], m = end - beg;
    if (t < 256) cnt[t] = 0;
    __syncthreads();
    int2 rv[12];
    int dr[12];
    int cv = 0;
    for (int i = t; i < m; i += 1024) {
        int2 r = rec[beg + i];
        int dn = ((unsigned)r.x >> 17) & 0xFF;
        int rnk = atomicAdd(&cnt[dn], 1);
        if (cv < 12) { rv[cv] = r; dr[cv] = dn | (rnk << 8); }
        cv++;                 // m <= 12288 always (bucket ~8192 + 45 sigma)
    }
    __syncthreads();
    int* s = cnt; int* d = tmp;
    for (int off = 1; off < 256; off <<= 1) {
        int v = 0;
        if (t < 256) v = s[t] + (t >= off ? s[t - off] : 0);
        __syncthreads();
        if (t < 256) d[t] = v;
        __syncthreads();
        int* tp = s; s = d; d = tp;
    }
    if (t < 256) ebase[t] = t ? s[t - 1] : 0;
    __syncthreads();
    if (t < NPB) row[n0 + t] = beg + ebase[t];
    int ncv = cv < 12 ? cv : 12;
    for (int k = 0; k < ncv; ++k) {
        int dn = dr[k] & 0xFF;
        int rnk = dr[k] >> 8;
        rec[beg + ebase[dn] + rnk] = rv[k];
    }
}

// ---- layer-0 transform, wave-per-64-nodes (h = x*W0 is rank-1) ----
// Writes hT (fp8), as_arr/ad_arr, AND fills asE[row[n]..row[n+1]) = as[n]
// via a monotone two-pointer walk (fused - no separate k_ase pass).
__global__ void k_transform0(const float* __restrict__ x, const float* __restrict__ W0,
                             const float* __restrict__ as_w, const float* __restrict__ ad_w,
                             unsigned short* __restrict__ hout, float* __restrict__ as_arr,
                             float* __restrict__ ad_arr, const int* __restrict__ row,
                             float* __restrict__ asE) {
    __shared__ float asl[4][64];
    __shared__ int rwl[4][65];
    int lane = threadIdx.x & 63;
    int wv = threadIdx.x >> 6;
    int nb = (blockIdx.x * 4 + wv) * 64;
    int n = nb + lane;
    float xv = x[n];
    rwl[wv][lane] = row[nb + lane];
    if (lane == 0) rwl[wv][64] = row[nb + 64];
    float c1 = 0.f, c2 = 0.f;
    float w0j[32];
#pragma unroll
    for (int j = 0; j < 32; ++j) {
        float wj = W0[j];
        w0j[j] = wj;
        c1 += wj * as_w[j];
        c2 += wj * ad_w[j];
    }
    float as = xv * c1, ad = xv * c2;
    as_arr[n] = as;
    ad_arr[n] = ad;
    asl[wv][lane] = as;
    int hwv[8];
#pragma unroll
    for (int q = 0; q < 8; ++q) {
        int w = 0;
        w = __builtin_amdgcn_cvt_pk_fp8_f32(xv * w0j[4 * q], xv * w0j[4 * q + 1], w, false);
        w = __builtin_amdgcn_cvt_pk_fp8_f32(xv * w0j[4 * q + 2], xv * w0j[4 * q + 3], w, true);
        hwv[q] = w;
    }
    int* hw = (int*)hout;
    *(int4*)&hw[n * 8] = make_int4(hwv[0], hwv[1], hwv[2], hwv[3]);
    *(int4*)&hw[n * 8 + 4] = make_int4(hwv[4], hwv[5], hwv[6], hwv[7]);
    // asE fill (same-wave LDS: in-order, no barrier needed)
    int e = rwl[wv][0] + lane;
    int eend = rwl[wv][64];
    int j = 0;
    for (; e < eend; e += 64) {
        while (rwl[wv][j + 1] <= e) ++j;
        asE[e] = asl[wv][j];
    }
}

// MFMA transform (R6) + fused asE fill.
__global__ void k_transform_m(const float* __restrict__ hin, const float* __restrict__ W,
                              const float* __restrict__ as_w, const float* __restrict__ ad_w,
                              unsigned short* __restrict__ hout, float* __restrict__ as_arr,
                              float* __restrict__ ad_arr, const int* __restrict__ row,
                              float* __restrict__ asE) {
    __shared__ float asl[4][64];
    __shared__ int rwl[4][65];
    int lane = threadIdx.x & 63;
    int wv = threadIdx.x >> 6;
    int col = lane & 15, hi = lane >> 4;
    int nb = (blockIdx.x * 4 + wv) * 64;     // 4 tiles x 16 nodes per wave
    rwl[wv][lane] = row[nb + lane];
    if (lane == 0) rwl[wv][64] = row[nb + 64];
    bf16x8 b0, b1;
#pragma unroll
    for (int e = 0; e < 8; ++e) {
        b0[e] = (short)f2bf(W[(hi * 8 + e) * 32 + col]);
        b1[e] = (short)f2bf(W[(hi * 8 + e) * 32 + col + 16]);
    }
    float asw0 = as_w[col], asw1 = as_w[col + 16];
    float adw0 = ad_w[col], adw1 = ad_w[col + 16];
    float4 a0[4], a1[4];
#pragma unroll
    for (int t = 0; t < 4; ++t) {
        const float* r = hin + (size_t)(nb + t * 16 + col) * 32 + hi * 8;
        a0[t] = *(const float4*)r;
        a1[t] = *(const float4*)(r + 4);
    }
    int* hw = (int*)hout;
#pragma unroll
    for (int t = 0; t < 4; ++t) {
        bf16x8 a;
        a[0] = (short)f2bf(a0[t].x); a[1] = (short)f2bf(a0[t].y);
        a[2] = (short)f2bf(a0[t].z); a[3] = (short)f2bf(a0[t].w);
        a[4] = (short)f2bf(a1[t].x); a[5] = (short)f2bf(a1[t].y);
        a[6] = (short)f2bf(a1[t].z); a[7] = (short)f2bf(a1[t].w);
        f32x4 z = {0.f, 0.f, 0.f, 0.f};
        f32x4 c0 = __builtin_amdgcn_mfma_f32_16x16x32_bf16(a, b0, z, 0, 0, 0);
        f32x4 c1 = __builtin_amdgcn_mfma_f32_16x16x32_bf16(a, b1, z, 0, 0, 0);
        int n0t = nb + t * 16;
#pragma unroll
        for (int i = 0; i < 4; ++i) {
            float pa = c0[i] * asw0 + c1[i] * asw1;
            float pd = c0[i] * adw0 + c1[i] * adw1;
#pragma unroll
            for (int m = 1; m <= 8; m <<= 1) {
                pa += __shfl_xor(pa, m);
                pd += __shfl_xor(pd, m);
            }
            float e0 = __shfl_xor(c0[i], 1), e1 = __shfl_xor(c1[i], 1);
            int pk0 = __builtin_amdgcn_cvt_pk_fp8_f32(c0[i], e0, 0, false);
            int pk1 = __builtin_amdgcn_cvt_pk_fp8_f32(c1[i], e1, 0, false);
            int q0 = __shfl_xor(pk0, 2), q1 = __shfl_xor(pk1, 2);
            int n = n0t + hi * 4 + i;
            if ((col & 3) == 0) {
                int w0 = (pk0 & 0xFFFF) | (q0 << 16);
                int w1 = (pk1 & 0xFFFF) | (q1 << 16);
                hw[(n << 3) + (col >> 2)] = w0;
                hw[(n << 3) + 4 + (col >> 2)] = w1;
            }
            if (col == 0) {
                as_arr[n] = pa;
                ad_arr[n] = pd;
                asl[wv][n - nb] = pa;
            }
        }
    }
    // asE fill (same-wave LDS writes precede reads in program order)
    int e = rwl[wv][0] + lane;
    int eend = rwl[wv][64];
    int j = 0;
    for (; e < eend; e += 64) {
        while (rwl[wv][j + 1] <= e) ++j;
        asE[e] = asl[wv][j];
    }
}

// accumulate one 4-fp8 word (4 dims) into 2 packed f32x2 accumulators
__device__ __forceinline__ void acc_word(float wp, int word, floatx2* acc) {
    floatx2 v01 = __builtin_amdgcn_cvt_pk_f32_fp8(word, false);
    floatx2 v23 = __builtin_amdgcn_cvt_pk_f32_fp8(word, true);
    floatx2 w2 = {wp, wp};
    acc[0] = __builtin_elementwise_fma(w2, v01, acc[0]);
    acc[1] = __builtin_elementwise_fma(w2, v23, acc[1]);
}

// k_gather: R10 asE variant (measured <=42 us; alpha_src read streaming).
__global__ void k_gather(const unsigned short* __restrict__ hT, const int2* __restrict__ rec,
                         const int* __restrict__ row, const float* __restrict__ asE,
                         const float* __restrict__ as_arr, const float* __restrict__ ad_arr,
                         const float* __restrict__ fold, const float* __restrict__ bias,
                         float* __restrict__ out, int do_relu) {
    const int* hw = (const int*)hT;     // row n = hw[n*8 + dl], 4 fp8 each
    __shared__ int2   exS[4][64];
    __shared__ float2 exW[4][64];
    int lane = threadIdx.x & 63;
    int wv = threadIdx.x >> 6;
    int slot = lane >> 3;     // 0..7
    int dl = lane & 7;        // 0..7 (dims dl*4 .. dl*4+3)
    const int* hwd = hw + dl;           // per-lane base; index with s<<3
    int nb = blockIdx.x * 16 + wv * 4;  // this wave's 4 nodes (2 pairs)
    int rowv[5];
#pragma unroll
    for (int i = 0; i < 5; ++i) rowv[i] = row[nb + i];
    float f0 = fold[0], f1 = fold[1];
    float4 bi = *(const float4*)(bias + 4 * dl);
    floatx2 zz = {0.f, 0.f};

    int2 r0[2], r1[2];
    float ae0[2], ae1[2];
#pragma unroll
    for (int k = 0; k < 2; ++k) {
        int beg0 = rowv[2 * k], end0 = rowv[2 * k + 1];
        int beg1 = rowv[2 * k + 1], end1 = rowv[2 * k + 2];
        int i0 = beg0 + lane; i0 = (i0 < end0) ? i0 : 0;
        int i1 = beg1 + lane; i1 = (i1 < end1) ? i1 : 0;
        r0[k] = rec[i0];
        r1[k] = rec[i1];
        ae0[k] = asE[i0];
        ae1[k] = asE[i1];
    }

#pragma unroll
    for (int k = 0; k < 2; ++k) {
        int beg0 = rowv[2 * k], end0 = rowv[2 * k + 1];
        int beg1 = rowv[2 * k + 1], end1 = rowv[2 * k + 2];
        int n0 = nb + 2 * k, n1 = n0 + 1;
        bool act0 = (beg0 + lane) < end0;
        bool act1 = (beg1 + lane) < end1;
        int s0 = r0[k].x & SRCMASK;
        int s1 = r1[k].x & SRCMASK;
        exS[wv][lane] = make_int2(s0 << 3, s1 << 3);
        int h0[8], h1[8];
#pragma unroll
        for (int p = 0; p < 8; ++p) {
            int2 sp = exS[wv][p * 8 + slot];
            h0[p] = hwd[sp.x];
            h1[p] = hwd[sp.y];
        }
        float a0 = ae0[k], a1 = ae1[k];
        float cd0 = ad_arr[n0], cd1 = ad_arr[n1];
        float ax0 = __uint_as_float((unsigned)r0[k].y << 16);
        float ay0 = __uint_as_float((unsigned)r0[k].y & 0xFFFF0000u);
        float ax1 = __uint_as_float((unsigned)r1[k].y << 16);
        float ay1 = __uint_as_float((unsigned)r1[k].y & 0xFFFF0000u);
        float ed0 = fmaf(ax0, f0, ay0 * f1);
        float ed1 = fmaf(ax1, f0, ay1 * f1);
        float lg0 = a0 + cd0 + ed0; lg0 = fmaxf(lg0, NEG * lg0);
        float lg1 = a1 + cd1 + ed1; lg1 = fmaxf(lg1, NEG * lg1);
        float w0 = act0 ? __expf(lg0) : 0.f;
        float w1 = act1 ? __expf(lg1) : 0.f;
        exW[wv][lane] = make_float2(w0, w1);
        float den0 = w0, den1 = w1;
        float es0 = act0 ? ed0 : 0.f;
        float es1 = act1 ? ed1 : 0.f;
        floatx2 acc0[2] = {zz, zz};
        floatx2 acc1[2] = {zz, zz};
#pragma unroll
        for (int p = 0; p < 8; ++p) {
            float2 wp = exW[wv][p * 8 + slot];
            acc_word(wp.x, h0[p], acc0);
            acc_word(wp.y, h1[p], acc1);
        }
        if (end0 - beg0 > 64 || end1 - beg1 > 64) {
            for (int e0 = beg0 + 64, e1 = beg1 + 64; e0 < end0 || e1 < end1;
                 e0 += 64, e1 += 64) {
                int i0 = e0 + lane; bool c0 = i0 < end0; i0 = c0 ? i0 : 0;
                int i1 = e1 + lane; bool c1 = i1 < end1; i1 = c1 ? i1 : 0;
                int2 q0 = rec[i0], q1 = rec[i1];
                float b0 = asE[i0], b1 = asE[i1];
                int t0 = q0.x & SRCMASK, t1 = q1.x & SRCMASK;
                exS[wv][lane] = make_int2(t0 << 3, t1 << 3);
                int g0[8], g1[8];
#pragma unroll
                for (int p = 0; p < 8; ++p) {
                    int2 sp = exS[wv][p * 8 + slot];
                    g0[p] = hwd[sp.x];
                    g1[p] = hwd[sp.y];
                }
                float bx0 = __uint_as_float((unsigned)q0.y << 16);
                float by0 = __uint_as_float((unsigned)q0.y & 0xFFFF0000u);
                float bx1 = __uint_as_float((unsigned)q1.y << 16);
                float by1 = __uint_as_float((unsigned)q1.y & 0xFFFF0000u);
                float fd0 = fmaf(bx0, f0, by0 * f1);
                float fd1 = fmaf(bx1, f0, by1 * f1);
                float mg0 = b0 + cd0 + fd0; mg0 = fmaxf(mg0, NEG * mg0);
                float mg1 = b1 + cd1 + fd1; mg1 = fmaxf(mg1, NEG * mg1);
                float v0 = c0 ? __expf(mg0) : 0.f;
                float v1 = c1 ? __expf(mg1) : 0.f;
                exW[wv][lane] = make_float2(v0, v1);
                den0 += v0; den1 += v1;
                es0 += c0 ? fd0 : 0.f;
                es1 += c1 ? fd1 : 0.f;
#pragma unroll
                for (int p = 0; p < 8; ++p) {
                    float2 wp = exW[wv][p * 8 + slot];
                    acc_word(wp.x, g0[p], acc0);
                    acc_word(wp.y, g1[p], acc1);
                }
            }
        }
        // ---- epilogue ----
        float* fA = (float*)acc0;
        float* fB = (float*)acc1;
#pragma unroll
        for (int m = 8; m <= 32; m <<= 1) {
#pragma unroll
            for (int q = 0; q < 4; ++q) {
                fA[q] += __shfl_xor(fA[q], m);
                fB[q] += __shfl_xor(fB[q], m);
            }
        }
#pragma unroll
        for (int m = 1; m <= 32; m <<= 1) {
            den0 += __shfl_xor(den0, m);
            den1 += __shfl_xor(den1, m);
            es0 += __shfl_xor(es0, m);
            es1 += __shfl_xor(es1, m);
        }
        int dg0 = end0 - beg0, dg1 = end1 - beg1;
        float el0 = es0 / fmaxf((float)dg0, 1.0f);
        float el1 = es1 / fmaxf((float)dg1, 1.0f);
        float lgs0 = as_arr[n0] + cd0 + el0; lgs0 = fmaxf(lgs0, NEG * lgs0);
        float lgs1 = as_arr[n1] + cd1 + el1; lgs1 = fmaxf(lgs1, NEG * lgs1);
        float ws0 = __expf(lgs0), ws1 = __expf(lgs1);
        den0 += ws0; den1 += ws1;
        acc_word(ws0, hwd[n0 << 3], acc0);   // self rows (uniform per wave)
        acc_word(ws1, hwd[n1 << 3], acc1);
        float rd0 = 1.0f / den0, rd1 = 1.0f / den1;
        float4 o0 = {fA[0] * rd0 + bi.x, fA[1] * rd0 + bi.y,
                     fA[2] * rd0 + bi.z, fA[3] * rd0 + bi.w};
        float4 o1 = {fB[0] * rd1 + bi.x, fB[1] * rd1 + bi.y,
                     fB[2] * rd1 + bi.z, fB[3] * rd1 + bi.w};
        if (do_relu) {
            o0.x = fmaxf(o0.x, 0.f); o0.y = fmaxf(o0.y, 0.f);
            o0.z = fmaxf(o0.z, 0.f); o0.w = fmaxf(o0.w, 0.f);
            o1.x = fmaxf(o1.x, 0.f); o1.y = fmaxf(o1.y, 0.f);
            o1.z = fmaxf(o1.z, 0.f); o1.w = fmaxf(o1.w, 0.f);
        }
        if (slot == 0) {
            *(float4*)(out + (n0 << 5) + (dl << 2)) = o0;
            *(float4*)(out + (n1 << 5) + (dl << 2)) = o1;
        }
    }
}

__global__ void k_pool(const float* __restrict__ h, const float* __restrict__ lw,
                       const float* __restrict__ lb, float* __restrict__ out) {
    int lane = threadIdx.x & 63;
    int g = blockIdx.x * 4 + (threadIdx.x >> 6);
    int j = lane & 31;
    int half = lane >> 5;
    const float* base = h + (size_t)g * NPG * HID;
    float acc = 0.f;
    for (int i = half; i < NPG; i += 2) acc += base[i * HID + j];
    acc += __shfl_xor(acc, 32);
    float v = acc * lw[j];
#pragma unroll
    for (int m = 16; m >= 1; m >>= 1) v += __shfl_xor(v, m);
    if (lane == 0) out[g] = fmaxf(v + lb[0], 0.f);
}

extern "C" void kernel_launch(void* const* d_in, const int* in_sizes, int n_in,
                              void* d_out, int out_size, void* d_ws, size_t ws_size,
                              hipStream_t stream) {
    const float* x        = (const float*)d_in[0];
    const int*   ei       = (const int*)d_in[1];
    const float* eattr    = (const float*)d_in[2];
    const float* W0       = (const float*)d_in[3];
    const float* Ws       = (const float*)d_in[4];
    const float* att_src  = (const float*)d_in[5];
    const float* att_dst  = (const float*)d_in[6];
    const float* We       = (const float*)d_in[7];
    const float* att_edge = (const float*)d_in[8];
    const float* bias     = (const float*)d_in[9];
    const float* lin_w    = (const float*)d_in[10];
    const float* lin_b    = (const float*)d_in[11];
    float* out = (float*)d_out;

    char* w = (char*)d_ws;
    int2*           rec    = (int2*)(w + O_REC);
    int*            cm     = (int*)(w + O_CM);
    unsigned short* hT     = (unsigned short*)(w + O_HT);
    float*          hB     = (float*)(w + O_HB);
    float*          as_arr = (float*)(w + O_AS);
    float*          ad_arr = (float*)(w + O_AD);
    int*            row    = (int*)(w + O_ROW);
    int*            btot   = (int*)(w + O_BTOT);
    int*            bbase  = (int*)(w + O_BBASE);
    float*          fold   = (float*)(w + O_FOLD);
    float*          asE    = (float*)(w + O_ASE);

    // ---- CSR build (write-clustered, contiguous rec, LDS-staged place) ----
    k_hist<<<NCH, 512, 0, stream>>>(ei + N_EDGES, cm);
    k_scanchunks<<<NB, 1024, 0, stream>>>(cm, btot);
    k_scanbuckets<<<1, NB, 0, stream>>>(btot, bbase, row, We, att_edge, fold);
    k_place<<<NCH, 512, 0, stream>>>(ei, (const float2*)eattr, cm, bbase, rec);
    k_sort<<<NB, 1024, 0, stream>>>(rec, bbase, row);

    // ---- layer 0 ----
    k_transform0<<<N_NODES / 256, 256, 0, stream>>>(x, W0, att_src, att_dst,
                                                    hT, as_arr, ad_arr, row, asE);
    k_gather<<<N_NODES / 16, 256, 0, stream>>>(hT, rec, row, asE, as_arr, ad_arr,
                                               fold, bias, hB, 1);
    // ---- layers 1..3 ----
    for (int l = 1; l < 4; ++l) {
        k_transform_m<<<N_NODES / 256, 256, 0, stream>>>(
            hB, Ws + (size_t)(l - 1) * HID * HID, att_src + l * HID, att_dst + l * HID,
            hT, as_arr, ad_arr, row, asE);
        k_gather<<<N_NODES / 16, 256, 0, stream>>>(hT, rec, row, asE, as_arr, ad_arr,
                                                   fold + 2 * l, bias + l * HID, hB,
                                                   (l < 3) ? 1 : 0);
    }

    // ---- pool + linear + relu ----
    k_pool<<<B_GR / 4, 256, 0, stream>>>(hB, lin_w, lin_b, out);
}